// Round 1
// 1449.155 us; speedup vs baseline: 1.0819x; 1.0819x over previous
//
#include <hip/hip_runtime.h>
#include <cstdint>
#include <cstddef>

#define BATCH 2
#define SEQ   256
#define DIM   512
#define NN    512
#define MM    16
#define NTICK 4
#define NSA   256
#define NSO   512
#define NHEAD 8
#define HDIM  64
#define VOCAB 32000
#define BS    (BATCH*SEQ)   // 512
#define NBLK  500           // VOCAB/64 col-panels for out_gemm3

typedef __bf16 bf16;
typedef bf16  bf16x4  __attribute__((ext_vector_type(4)));
typedef bf16  bf16x8v __attribute__((ext_vector_type(8)));
typedef float f32x4   __attribute__((ext_vector_type(4)));

typedef __attribute__((address_space(1))) const void av1_t;
typedef __attribute__((address_space(3))) void av3_t;

// ---------------------------------------------------------------- embedding
__global__ __launch_bounds__(128) void embed_kernel(const int* __restrict__ x,
    const float* __restrict__ tok, const float* __restrict__ pos, float* __restrict__ out){
  int row = blockIdx.x;               // b*SEQ + s
  int s = row & (SEQ-1);
  int token = x[row];
  const float4* tr = (const float4*)(tok + (size_t)token*DIM);
  const float4* pr = (const float4*)(pos + (size_t)s*DIM);
  float4* orow = (float4*)(out + (size_t)row*DIM);
  for (int i = threadIdx.x; i < DIM/4; i += blockDim.x){
    float4 a = tr[i], b = pr[i];
    float4 o; o.x=a.x+b.x; o.y=a.y+b.y; o.z=a.z+b.z; o.w=a.w+b.w;
    orow[i] = o;
  }
}

// ---------------------------------------------------------------- LayerNorm over 512
__global__ __launch_bounds__(256) void ln512_kernel(const float* __restrict__ in,
    const float* __restrict__ g, const float* __restrict__ b, float* __restrict__ out){
  int row = blockIdx.x, tid = threadIdx.x;
  const float* xr = in + (size_t)row*512;
  float v0 = xr[tid], v1 = xr[tid+256];
  float s = v0+v1, ss = v0*v0+v1*v1;
  #pragma unroll
  for (int o = 32; o > 0; o >>= 1){ s += __shfl_down(s, o); ss += __shfl_down(ss, o); }
  __shared__ float rs[4], rss[4];
  __shared__ float smean, sinv;
  int wid = tid >> 6, lane = tid & 63;
  if (lane == 0){ rs[wid] = s; rss[wid] = ss; }
  __syncthreads();
  if (tid == 0){
    float S = rs[0]+rs[1]+rs[2]+rs[3];
    float SS = rss[0]+rss[1]+rss[2]+rss[3];
    float m = S * (1.0f/512.0f);
    float var = SS * (1.0f/512.0f) - m*m;
    smean = m; sinv = 1.0f/sqrtf(var + 1e-5f);
  }
  __syncthreads();
  float m = smean, inv = sinv;
  out[(size_t)row*512 + tid]       = (v0-m)*inv*g[tid]     + b[tid];
  out[(size_t)row*512 + tid + 256] = (v1-m)*inv*g[tid+256] + b[tid+256];
}

// ---------------------------------------------------------------- GLU(1024->512) + LN
__global__ __launch_bounds__(256) void glu_ln_kernel(const float* __restrict__ y,
    const float* __restrict__ g, const float* __restrict__ beta, float* __restrict__ out){
  int row = blockIdx.x, tid = threadIdx.x;
  const float* yr = y + (size_t)row*1024;
  float a0 = yr[tid],     b0 = yr[tid+512];
  float a1 = yr[tid+256], b1 = yr[tid+768];
  float g0 = a0 / (1.0f + expf(-b0));
  float g1 = a1 / (1.0f + expf(-b1));
  float s = g0+g1, ss = g0*g0+g1*g1;
  #pragma unroll
  for (int o = 32; o > 0; o >>= 1){ s += __shfl_down(s, o); ss += __shfl_down(ss, o); }
  __shared__ float rs[4], rss[4];
  __shared__ float smean, sinv;
  int wid = tid >> 6, lane = tid & 63;
  if (lane == 0){ rs[wid] = s; rss[wid] = ss; }
  __syncthreads();
  if (tid == 0){
    float S = rs[0]+rs[1]+rs[2]+rs[3];
    float SS = rss[0]+rss[1]+rss[2]+rss[3];
    float m = S * (1.0f/512.0f);
    float var = SS * (1.0f/512.0f) - m*m;
    smean = m; sinv = 1.0f/sqrtf(var + 1e-5f);
  }
  __syncthreads();
  float m = smean, inv = sinv;
  out[(size_t)row*512 + tid]       = (g0-m)*inv*g[tid]     + beta[tid];
  out[(size_t)row*512 + tid + 256] = (g1-m)*inv*g[tid+256] + beta[tid+256];
}

// ---------------------------------------------------------------- sync accumulators
__global__ __launch_bounds__(256) void sync_kernel(const float* __restrict__ act,
    const int* __restrict__ il, const int* __restrict__ ir, const float* __restrict__ decay,
    float* __restrict__ accA, float* __restrict__ accB,
    float* __restrict__ outf, bf16* __restrict__ outb, int NS, int first){
  int i = blockIdx.x*256 + threadIdx.x;
  if (i >= BS*NS) return;
  int bs = i / NS, c = i - bs*NS;
  const float* ar = act + (size_t)bs*NN;
  float p = ar[il[c]] * ar[ir[c]];
  float A, Bv;
  if (first){ A = p; Bv = 1.0f; }
  else {
    float r = expf(-decay[c]);
    A = r*accA[i] + p;
    Bv = r*accB[i] + 1.0f;
  }
  accA[i] = A; accB[i] = Bv;
  float sy = A / sqrtf(Bv + 1e-8f);
  if (outf) outf[i] = sy;
  if (outb) outb[i] = (bf16)sy;
}

// ---------------------------------------------------------------- split+transpose weight
// W f32 [K][N] -> hiT,loT bf16 [N][K].  loT may be null (hi-only, for out_w).
__global__ __launch_bounds__(256) void split_t(const float* __restrict__ W,
    bf16* __restrict__ hiT, bf16* __restrict__ loT, int K, int N){
  __shared__ float t[32][33];
  int n0 = blockIdx.x*32, k0 = blockIdx.y*32;
  int tid = threadIdx.x;
  int r = tid >> 3, c4 = (tid & 7)*4;
  float4 v = *(const float4*)(W + (size_t)(k0+r)*N + n0 + c4);
  t[r][c4+0]=v.x; t[r][c4+1]=v.y; t[r][c4+2]=v.z; t[r][c4+3]=v.w;
  __syncthreads();
  bf16x4 hi, lo;
  #pragma unroll
  for (int j = 0; j < 4; j++){
    float a = t[c4+j][r];
    bf16 h = (bf16)a;
    hi[j] = h;
    lo[j] = (bf16)(a - (float)h);
  }
  *(bf16x4*)(hiT + (size_t)(n0+r)*K + k0 + c4) = hi;
  if (loT) *(bf16x4*)(loT + (size_t)(n0+r)*K + k0 + c4) = lo;
}

// ---------------------------------------------------------------- bf16x3 MFMA GEMM
// C[M,N] = A(f32)[M,K] @ W + bias, with W pre-split WhT/WlT bf16 [N][K].
// 1 wave/block: 16 m-rows x 64 n-cols.  grid = (N/64, M/16).
__global__ __launch_bounds__(64) void gemm_x3(
    const float* __restrict__ A, const bf16* __restrict__ WhT,
    const bf16* __restrict__ WlT, const float* __restrict__ bias,
    float* __restrict__ C, int K, int lda, int ldc){
  int n0 = blockIdx.x * 64, m0 = blockIdx.y * 16;
  int lane = threadIdx.x;
  int ln = lane & 15, kq = lane >> 4;
  f32x4 acc[4];
  #pragma unroll
  for (int nf = 0; nf < 4; nf++) acc[nf] = (f32x4){0.f,0.f,0.f,0.f};
  const float* arow = A + (size_t)(m0 + ln)*lda + kq*8;
  const bf16* w0h = WhT + (size_t)(n0 + ln)*K + kq*8;
  const bf16* w0l = WlT + (size_t)(n0 + ln)*K + kq*8;
  size_t nstep = (size_t)16*K;
  for (int k0 = 0; k0 < K; k0 += 32){
    float4 a0 = *(const float4*)(arow + k0);
    float4 a1 = *(const float4*)(arow + k0 + 4);
    float av[8] = {a0.x,a0.y,a0.z,a0.w,a1.x,a1.y,a1.z,a1.w};
    bf16x8v ahi, alo;
    #pragma unroll
    for (int j = 0; j < 8; j++){
      bf16 h = (bf16)av[j];
      ahi[j] = h;
      alo[j] = (bf16)(av[j] - (float)h);
    }
    #pragma unroll
    for (int nf = 0; nf < 4; nf++){
      bf16x8v bh = *(const bf16x8v*)(w0h + nf*nstep + k0);
      bf16x8v bl = *(const bf16x8v*)(w0l + nf*nstep + k0);
      acc[nf] = __builtin_amdgcn_mfma_f32_16x16x32_bf16(ahi, bh, acc[nf], 0,0,0);
      acc[nf] = __builtin_amdgcn_mfma_f32_16x16x32_bf16(alo, bh, acc[nf], 0,0,0);
      acc[nf] = __builtin_amdgcn_mfma_f32_16x16x32_bf16(ahi, bl, acc[nf], 0,0,0);
    }
  }
  #pragma unroll
  for (int nf = 0; nf < 4; nf++){
    int col = n0 + nf*16 + ln;
    float bb = bias ? bias[col] : 0.0f;
    #pragma unroll
    for (int r = 0; r < 4; r++)
      C[(size_t)(m0 + kq*4 + r)*ldc + col] = acc[nf][r] + bb;
  }
}

// ---------------------------------------------------------------- bias vec: qbc = q_b@wq + bq
__global__ void qbc_kernel(const float* __restrict__ qb, const float* __restrict__ wq,
                           const float* __restrict__ bq, float* __restrict__ qbc){
  int j = blockIdx.x*64 + threadIdx.x;
  float s = bq[j];
  for (int k = 0; k < DIM; k++) s = fmaf(qb[k], wq[(size_t)k*DIM + j], s);
  qbc[j] = s;
}

// ---------------------------------------------------------------- attention (per b,h, 16-query tile)
__global__ __launch_bounds__(256) void attn_kernel(const float* __restrict__ qh,
    const float* __restrict__ kb, const float* __restrict__ vb, float* __restrict__ outb){
  int qt = blockIdx.x, h = blockIdx.y, b = blockIdx.z;
  __shared__ float qs[16][HDIM];
  __shared__ float sc[16][SEQ + 4];
  __shared__ float red[16][16];
  __shared__ float rowm[16], rowz[16];
  int tid = threadIdx.x;
  {
    int r = tid >> 4, c4 = tid & 15;
    *(float4*)&qs[r][c4*4] =
      *(const float4*)(qh + ((size_t)(b*SEQ + qt*16 + r))*DIM + h*HDIM + c4*4);
  }
  __syncthreads();
  {
    int kk = tid;
    const float* krow = kb + ((size_t)(b*SEQ + kk))*DIM + h*HDIM;
    float s[16] = {};
    for (int d4 = 0; d4 < HDIM/4; d4++){
      float4 k4 = *(const float4*)(krow + d4*4);
      #pragma unroll
      for (int q = 0; q < 16; q++){
        float4 q4 = *(const float4*)&qs[q][d4*4];
        s[q] += q4.x*k4.x + q4.y*k4.y + q4.z*k4.z + q4.w*k4.w;
      }
    }
    #pragma unroll
    for (int q = 0; q < 16; q++){
      int qg = qt*16 + q;
      sc[q][kk] = (kk > qg) ? -1e9f : s[q]*0.125f;
    }
  }
  __syncthreads();
  {
    int q = tid >> 4, seg = tid & 15;
    float m = -1e30f;
    for (int i = 0; i < 16; i++) m = fmaxf(m, sc[q][seg*16+i]);
    red[q][seg] = m;
  }
  __syncthreads();
  if (tid < 16){
    float m = red[tid][0];
    for (int i = 1; i < 16; i++) m = fmaxf(m, red[tid][i]);
    rowm[tid] = m;
  }
  __syncthreads();
  {
    int q = tid >> 4, seg = tid & 15;
    float m = rowm[q], z = 0.0f;
    for (int i = 0; i < 16; i++){
      float e = expf(sc[q][seg*16+i] - m);
      sc[q][seg*16+i] = e;
      z += e;
    }
    red[q][seg] = z;
  }
  __syncthreads();
  if (tid < 16){
    float z = 0.0f;
    for (int i = 0; i < 16; i++) z += red[tid][i];
    rowz[tid] = 1.0f / z;
  }
  __syncthreads();
  {
    int q = tid >> 4, dc = tid & 15;
    float inv = rowz[q];
    float ax=0, ay=0, az=0, aw=0;
    for (int kk = 0; kk < SEQ; kk++){
      float p = sc[q][kk];
      float4 v4 = *(const float4*)(vb + ((size_t)(b*SEQ + kk))*DIM + h*HDIM + dc*4);
      ax = fmaf(p, v4.x, ax); ay = fmaf(p, v4.y, ay);
      az = fmaf(p, v4.z, az); aw = fmaf(p, v4.w, aw);
    }
    float4 o; o.x=ax*inv; o.y=ay*inv; o.z=az*inv; o.w=aw*inv;
    *(float4*)(outb + ((size_t)(b*SEQ + qt*16 + q))*DIM + h*HDIM + dc*4) = o;
  }
}

// ---------------------------------------------------------------- copies
__global__ void act_init_kernel(const float* __restrict__ sa, float* __restrict__ act){
  int i = blockIdx.x*256 + threadIdx.x;
  act[i] = sa[i & (SEQ*NN - 1)];
}
__global__ void cat_act_kernel(const float* __restrict__ act, float* __restrict__ cat){
  int i = blockIdx.x*256 + threadIdx.x;
  int bs = i >> 9, n = i & 511;
  cat[(size_t)bs*1024 + 512 + n] = act[i];
}

// ---------------------------------------------------------------- per-neuron NLM
__global__ __launch_bounds__(256) void nlm_kernel(
    const float* __restrict__ start_trace,
    const float* __restrict__ s0, const float* __restrict__ s1,
    const float* __restrict__ s2, const float* __restrict__ s3,
    const float* __restrict__ fc1w, const float* __restrict__ fc1b,
    const float* __restrict__ fc2w, const float* __restrict__ fc2b,
    const float* __restrict__ nlmT, float* __restrict__ act, int t){
  int n = blockIdx.x, b = blockIdx.y, s = threadIdx.x;
  int bs = b*SEQ + s;
  size_t sidx = (size_t)bs*NN + n;
  float tr[16];
  #pragma unroll
  for (int j = 0; j < 16; j++){
    int src = j + t + 1;
    if (src < 16){
      tr[j] = start_trace[((size_t)s*NN + n)*MM + src];
    } else {
      int k = src - 16;
      tr[j] = (k==0) ? s0[sidx] : (k==1) ? s1[sidx] : (k==2) ? s2[sidx] : s3[sidx];
    }
  }
  const float* w1 = fc1w + (size_t)n*16*256;
  const float* b1 = fc1b + (size_t)n*256;
  const float* w2 = fc2w + (size_t)n*256;
  float o0 = fc2b[n*2+0], o1 = fc2b[n*2+1];
  #pragma unroll 4
  for (int j = 0; j < 128; j++){
    float a  = b1[j];
    float bb = b1[j+128];
    #pragma unroll
    for (int m = 0; m < 16; m++){
      a  = fmaf(tr[m], w1[m*256 + j],       a);
      bb = fmaf(tr[m], w1[m*256 + j + 128], bb);
    }
    float gg = a / (1.0f + expf(-bb));
    o0 = fmaf(gg, w2[j*2+0], o0);
    o1 = fmaf(gg, w2[j*2+1], o1);
  }
  float o = o0 / (1.0f + expf(-o1));
  act[sidx] = o / nlmT[0];
}

// ---------------------------------------------------------------- vocab GEMM v3
// One block per 64-col WoT panel (grid = 500).  Panel (64x512 bf16 = 64 KB,
// contiguous in memory) staged ONCE into LDS via global_load_lds with
// pre-swizzled source; ds_read side applies the matching XOR swizzle
// (byte ^= (col&7)<<4) to kill the 1024B-stride bank conflict.
// 4 waves; wave w sweeps m-tiles m0 = w*16 + i*64 (i=0..7), 4 ticks each:
// per K-step 16 MFMA : 4 global + 4 LDS loads.  Entropy partials are
// wave-private per 64-col slice (no cross-wave reduction, NBLK=500).
__global__ __launch_bounds__(256) void out_gemm3(
    const bf16* __restrict__ sy0, const bf16* __restrict__ sy1,
    const bf16* __restrict__ sy2, const bf16* __restrict__ sy3,
    const bf16* __restrict__ WoT, const float* __restrict__ bo,
    float* __restrict__ outp, float* __restrict__ pm,
    float* __restrict__ pz, float* __restrict__ ps){
  __shared__ bf16 Bs[64*512];          // 64 KB, [col][K], XOR-swizzled
  int tid = threadIdx.x;
  int w = tid >> 6, lane = tid & 63;
  int ln = lane & 15, kq = lane >> 4;
  int n0 = blockIdx.x * 64;

  { // ---- stage panel: linear LDS dest (wave-uniform base), swizzled global src
    const char* gp = (const char*)(WoT + (size_t)n0*512);
    char* lp = (char*)Bs;
    #pragma unroll
    for (int it = 0; it < 16; ++it){
      int ub = (w*16 + it) << 10;                    // wave-uniform LDS base
      int b  = ub + lane*16;                         // this lane's dest byte
      int src = b ^ (((b >> 10) & 7) << 4);          // inverse(=same) swizzle
      __builtin_amdgcn_global_load_lds((av1_t*)(gp + src), (av3_t*)(lp + ub),
                                       16, 0, 0);
    }
  }
  __syncthreads();

  float bb[4];
  #pragma unroll
  for (int nf = 0; nf < 4; ++nf) bb[nf] = bo[n0 + nf*16 + ln];

  const size_t aoff = (size_t)ln*512 + (size_t)kq*8;
  const char* Bsc = (const char*)Bs;
  const int bbase = (ln << 10) + (kq << 4);          // col-lane + k-quad base
  const int sw = (ln & 7) << 4;                      // bank swizzle

  for (int i = 0; i < 8; ++i){
    int m0 = w*16 + i*64;
    const bf16* pa0 = sy0 + (size_t)m0*512 + aoff;
    const bf16* pa1 = sy1 + (size_t)m0*512 + aoff;
    const bf16* pa2 = sy2 + (size_t)m0*512 + aoff;
    const bf16* pa3 = sy3 + (size_t)m0*512 + aoff;
    f32x4 acc[4][4];                                 // [tick][nf]
    #pragma unroll
    for (int t = 0; t < 4; ++t)
      #pragma unroll
      for (int nf = 0; nf < 4; ++nf) acc[t][nf] = (f32x4){0.f,0.f,0.f,0.f};

    #pragma unroll
    for (int k0 = 0; k0 < 512; k0 += 32){
      bf16x8v a0 = *(const bf16x8v*)(pa0 + k0);
      bf16x8v a1 = *(const bf16x8v*)(pa1 + k0);
      bf16x8v a2 = *(const bf16x8v*)(pa2 + k0);
      bf16x8v a3 = *(const bf16x8v*)(pa3 + k0);
      int kb = bbase + k0*2;
      bf16x8v b0 = *(const bf16x8v*)(Bsc + ((kb           ) ^ sw));
      bf16x8v b1 = *(const bf16x8v*)(Bsc + ((kb + 16*1024) ^ sw));
      bf16x8v b2 = *(const bf16x8v*)(Bsc + ((kb + 32*1024) ^ sw));
      bf16x8v b3 = *(const bf16x8v*)(Bsc + ((kb + 48*1024) ^ sw));
      acc[0][0] = __builtin_amdgcn_mfma_f32_16x16x32_bf16(a0, b0, acc[0][0], 0,0,0);
      acc[1][0] = __builtin_amdgcn_mfma_f32_16x16x32_bf16(a1, b0, acc[1][0], 0,0,0);
      acc[2][0] = __builtin_amdgcn_mfma_f32_16x16x32_bf16(a2, b0, acc[2][0], 0,0,0);
      acc[3][0] = __builtin_amdgcn_mfma_f32_16x16x32_bf16(a3, b0, acc[3][0], 0,0,0);
      acc[0][1] = __builtin_amdgcn_mfma_f32_16x16x32_bf16(a0, b1, acc[0][1], 0,0,0);
      acc[1][1] = __builtin_amdgcn_mfma_f32_16x16x32_bf16(a1, b1, acc[1][1], 0,0,0);
      acc[2][1] = __builtin_amdgcn_mfma_f32_16x16x32_bf16(a2, b1, acc[2][1], 0,0,0);
      acc[3][1] = __builtin_amdgcn_mfma_f32_16x16x32_bf16(a3, b1, acc[3][1], 0,0,0);
      acc[0][2] = __builtin_amdgcn_mfma_f32_16x16x32_bf16(a0, b2, acc[0][2], 0,0,0);
      acc[1][2] = __builtin_amdgcn_mfma_f32_16x16x32_bf16(a1, b2, acc[1][2], 0,0,0);
      acc[2][2] = __builtin_amdgcn_mfma_f32_16x16x32_bf16(a2, b2, acc[2][2], 0,0,0);
      acc[3][2] = __builtin_amdgcn_mfma_f32_16x16x32_bf16(a3, b2, acc[3][2], 0,0,0);
      acc[0][3] = __builtin_amdgcn_mfma_f32_16x16x32_bf16(a0, b3, acc[0][3], 0,0,0);
      acc[1][3] = __builtin_amdgcn_mfma_f32_16x16x32_bf16(a1, b3, acc[1][3], 0,0,0);
      acc[2][3] = __builtin_amdgcn_mfma_f32_16x16x32_bf16(a2, b3, acc[2][3], 0,0,0);
      acc[3][3] = __builtin_amdgcn_mfma_f32_16x16x32_bf16(a3, b3, acc[3][3], 0,0,0);
    }

    // ---- bias
    #pragma unroll
    for (int t = 0; t < 4; ++t)
      #pragma unroll
      for (int nf = 0; nf < 4; ++nf)
        #pragma unroll
        for (int r = 0; r < 4; ++r) acc[t][nf][r] += bb[nf];

    // ---- store preds: float4 = 4 ticks per vocab entry, coalesced per 16-lane group
    #pragma unroll
    for (int r = 0; r < 4; ++r){
      size_t rowoff = (size_t)(m0 + kq*4 + r)*VOCAB;
      #pragma unroll
      for (int nf = 0; nf < 4; ++nf){
        float4 o;
        o.x = acc[0][nf][r]; o.y = acc[1][nf][r];
        o.z = acc[2][nf][r]; o.w = acc[3][nf][r];
        *(float4*)(outp + (rowoff + n0 + nf*16 + ln)*4) = o;
      }
    }

    // ---- entropy partials over this block's 64 cols (wave-private)
    #pragma unroll
    for (int t = 0; t < 4; ++t){
      #pragma unroll
      for (int r = 0; r < 4; ++r){
        float m = fmaxf(fmaxf(acc[t][0][r], acc[t][1][r]),
                        fmaxf(acc[t][2][r], acc[t][3][r]));
        #pragma unroll
        for (int o2 = 1; o2 < 16; o2 <<= 1) m = fmaxf(m, __shfl_xor(m, o2));
        float z = 0.0f, s = 0.0f;
        #pragma unroll
        for (int nf = 0; nf < 4; ++nf){
          float v = acc[t][nf][r] - m;
          float e = expf(v);
          z += e; s += v*e;
        }
        #pragma unroll
        for (int o2 = 1; o2 < 16; o2 <<= 1){ z += __shfl_xor(z, o2); s += __shfl_xor(s, o2); }
        if (ln == 0){
          size_t p = ((size_t)(m0 + kq*4 + r)*4 + t)*NBLK + blockIdx.x;
          pm[p] = m; pz[p] = z; ps[p] = s;
        }
      }
    }
  }
}

// ---------------------------------------------------------------- entropy finalize
__global__ __launch_bounds__(64) void ent_final(const float* __restrict__ pm,
    const float* __restrict__ pz, const float* __restrict__ ps, float* __restrict__ certs){
  int row = blockIdx.x >> 2, t = blockIdx.x & 3;
  const size_t base = ((size_t)row*4 + t)*NBLK;
  int lane = threadIdx.x;
  float M = -1e30f, Z = 0.0f, S = 0.0f;
  for (int i = lane; i < NBLK; i += 64){
    float m2 = pm[base+i], z2 = pz[base+i], s2 = ps[base+i];
    float Mn = fmaxf(M, m2);
    float e1 = expf(M - Mn), e2 = expf(m2 - Mn);
    S = (S + (M - Mn)*Z)*e1 + (s2 + (m2 - Mn)*z2)*e2;
    Z = Z*e1 + z2*e2;
    M = Mn;
  }
  #pragma unroll
  for (int o = 1; o < 64; o <<= 1){
    float m2 = __shfl_xor(M, o), z2 = __shfl_xor(Z, o), s2 = __shfl_xor(S, o);
    float Mn = fmaxf(M, m2);
    float e1 = expf(M - Mn), e2 = expf(m2 - Mn);
    S = (S + (M - Mn)*Z)*e1 + (s2 + (m2 - Mn)*z2)*e2;
    Z = Z*e1 + z2*e2;
    M = Mn;
  }
  if (lane == 0){
    float ent = (logf(Z) - S/Z) * (1.0f / logf((float)VOCAB));
    certs[((size_t)row*2 + 0)*4 + t] = ent;
    certs[((size_t)row*2 + 1)*4 + t] = 1.0f - ent;
  }
}

// ================================================================ host
extern "C" void kernel_launch(void* const* d_in, const int* in_sizes, int n_in,
                              void* d_out, int out_size, void* d_ws, size_t ws_size,
                              hipStream_t stream){
  const int*   x        = (const int*)  d_in[0];
  const float* tok      = (const float*)d_in[1];
  const float* pos      = (const float*)d_in[2];
  const float* ln_emb_g = (const float*)d_in[3];
  const float* ln_emb_b = (const float*)d_in[4];
  const float* kv_w     = (const float*)d_in[5];
  const float* kv_b     = (const float*)d_in[6];
  const float* kv_ln_g  = (const float*)d_in[7];
  const float* kv_ln_b  = (const float*)d_in[8];
  const float* q_w      = (const float*)d_in[9];
  const float* q_b      = (const float*)d_in[10];
  const float* wq       = (const float*)d_in[11];
  const float* bq       = (const float*)d_in[12];
  const float* wk       = (const float*)d_in[13];
  const float* bk       = (const float*)d_in[14];
  const float* wv       = (const float*)d_in[15];
  const float* bv       = (const float*)d_in[16];
  const float* ow       = (const float*)d_in[17];
  const float* ob       = (const float*)d_in[18];
  const float* syn_w    = (const float*)d_in[19];
  const float* syn_b    = (const float*)d_in[20];
  const float* syn_g    = (const float*)d_in[21];
  const float* syn_beta = (const float*)d_in[22];
  const float* fc1_w    = (const float*)d_in[23];
  const float* fc1_b    = (const float*)d_in[24];
  const float* fc2_w    = (const float*)d_in[25];
  const float* fc2_b    = (const float*)d_in[26];
  const float* nlm_T    = (const float*)d_in[27];
  const float* start_act   = (const float*)d_in[28];
  const float* start_trace = (const float*)d_in[29];
  const float* decay_a  = (const float*)d_in[30];
  const float* decay_o  = (const float*)d_in[31];
  const float* out_w    = (const float*)d_in[32];
  const float* out_b    = (const float*)d_in[33];
  const int* idx_al = (const int*)d_in[34];
  const int* idx_ar = (const int*)d_in[35];
  const int* idx_ol = (const int*)d_in[36];
  const int* idx_or = (const int*)d_in[37];

  char* wp = (char*)d_ws;
  auto alloc = [&](size_t bytes) -> void* {
    void* p = (void*)wp;
    wp += (bytes + 255) & ~(size_t)255;
    return p;
  };
  // f32 activations
  float* qwc      = (float*)alloc((size_t)256*512*4);
  float* qbc      = (float*)alloc(512*4);
  float* emb_raw  = (float*)alloc((size_t)BS*512*4);
  float* emb      = (float*)alloc((size_t)BS*512*4);
  float* kvt      = (float*)alloc((size_t)BS*512*4);
  float* kvn      = (float*)alloc((size_t)BS*512*4);
  float* kbuf     = (float*)alloc((size_t)BS*512*4);
  float* vbuf     = (float*)alloc((size_t)BS*512*4);
  float* act      = (float*)alloc((size_t)BS*512*4);
  float* aaB      = (float*)alloc((size_t)BS*256*4);
  float* baB      = (float*)alloc((size_t)BS*256*4);
  float* aoB      = (float*)alloc((size_t)BS*512*4);
  float* boB      = (float*)alloc((size_t)BS*512*4);
  float* sync_a   = (float*)alloc((size_t)BS*256*4);
  float* qh       = (float*)alloc((size_t)BS*512*4);
  float* attn_raw = (float*)alloc((size_t)BS*512*4);
  float* catb     = (float*)alloc((size_t)BS*1024*4);
  float* syn_y    = (float*)alloc((size_t)BS*1024*4);
  float* states[NTICK];
  for (int t = 0; t < NTICK; t++) states[t] = (float*)alloc((size_t)BS*512*4);
  bf16* syob[NTICK];
  for (int t = 0; t < NTICK; t++) syob[t] = (bf16*)alloc((size_t)BS*512*2);
  // split weights (bf16, transposed [N][K])
  bf16* kvT_h = (bf16*)alloc((size_t)512*512*2);
  bf16* kvT_l = (bf16*)alloc((size_t)512*512*2);
  bf16* wkT_h = (bf16*)alloc((size_t)512*512*2);
  bf16* wkT_l = (bf16*)alloc((size_t)512*512*2);
  bf16* wvT_h = (bf16*)alloc((size_t)512*512*2);
  bf16* wvT_l = (bf16*)alloc((size_t)512*512*2);
  bf16* owT_h = (bf16*)alloc((size_t)512*512*2);
  bf16* owT_l = (bf16*)alloc((size_t)512*512*2);
  bf16* wqT_h = (bf16*)alloc((size_t)512*512*2);
  bf16* wqT_l = (bf16*)alloc((size_t)512*512*2);
  bf16* synT_h = (bf16*)alloc((size_t)1024*1024*2);
  bf16* synT_l = (bf16*)alloc((size_t)1024*1024*2);
  bf16* qwcT_h = (bf16*)alloc((size_t)512*256*2);
  bf16* qwcT_l = (bf16*)alloc((size_t)512*256*2);
  bf16* WoT    = (bf16*)alloc((size_t)VOCAB*512*2);
  // entropy partials
  float* pm = (float*)alloc((size_t)BS*4*NBLK*4);
  float* pz = (float*)alloc((size_t)BS*4*NBLK*4);
  float* ps = (float*)alloc((size_t)BS*4*NBLK*4);

  float* preds = (float*)d_out;
  float* certs = (float*)d_out + (size_t)BS*VOCAB*NTICK;

  // ---- weight prep
  split_t<<<dim3(16,16), 256, 0, stream>>>(kv_w,  kvT_h, kvT_l, 512, 512);
  split_t<<<dim3(16,16), 256, 0, stream>>>(wk,    wkT_h, wkT_l, 512, 512);
  split_t<<<dim3(16,16), 256, 0, stream>>>(wv,    wvT_h, wvT_l, 512, 512);
  split_t<<<dim3(16,16), 256, 0, stream>>>(ow,    owT_h, owT_l, 512, 512);
  split_t<<<dim3(16,16), 256, 0, stream>>>(wq,    wqT_h, wqT_l, 512, 512);
  split_t<<<dim3(32,32), 256, 0, stream>>>(syn_w, synT_h, synT_l, 1024, 1024);
  split_t<<<dim3(VOCAB/32,16), 256, 0, stream>>>(out_w, WoT, nullptr, 512, VOCAB);

  // ---- pre
  embed_kernel<<<BS, 128, 0, stream>>>(x, tok, pos, emb_raw);
  ln512_kernel<<<BS, 256, 0, stream>>>(emb_raw, ln_emb_g, ln_emb_b, emb);
  gemm_x3<<<dim3(8,32), 64, 0, stream>>>(emb, kvT_h, kvT_l, kv_b, kvt, 512, 512, 512);
  ln512_kernel<<<BS, 256, 0, stream>>>(kvt, kv_ln_g, kv_ln_b, kvn);
  gemm_x3<<<dim3(8,32), 64, 0, stream>>>(kvn, wkT_h, wkT_l, bk, kbuf, 512, 512, 512);
  gemm_x3<<<dim3(8,32), 64, 0, stream>>>(kvn, wvT_h, wvT_l, bv, vbuf, 512, 512, 512);
  gemm_x3<<<dim3(8,16), 64, 0, stream>>>(q_w, wqT_h, wqT_l, nullptr, qwc, 512, 512, 512);
  split_t<<<dim3(16,8), 256, 0, stream>>>(qwc, qwcT_h, qwcT_l, 256, 512);
  qbc_kernel<<<8, 64, 0, stream>>>(q_b, wq, bq, qbc);
  act_init_kernel<<<(BS*NN)/256, 256, 0, stream>>>(start_act, act);

  // ---- ticks
  for (int t = 0; t < NTICK; t++){
    sync_kernel<<<(BS*NSA)/256, 256, 0, stream>>>(act, idx_al, idx_ar, decay_a,
        aaB, baB, sync_a, nullptr, NSA, t==0);
    gemm_x3<<<dim3(8,32), 64, 0, stream>>>(sync_a, qwcT_h, qwcT_l, qbc, qh, 256, 256, 512);
    attn_kernel<<<dim3(16, NHEAD, BATCH), 256, 0, stream>>>(qh, kbuf, vbuf, attn_raw);
    gemm_x3<<<dim3(8,32), 64, 0, stream>>>(attn_raw, owT_h, owT_l, ob, catb, 512, 512, 1024);
    cat_act_kernel<<<(BS*NN)/256, 256, 0, stream>>>(act, catb);
    gemm_x3<<<dim3(16,32), 64, 0, stream>>>(catb, synT_h, synT_l, syn_b, syn_y, 1024, 1024, 1024);
    glu_ln_kernel<<<BS, 256, 0, stream>>>(syn_y, syn_g, syn_beta, states[t]);
    nlm_kernel<<<dim3(NN, BATCH), 256, 0, stream>>>(start_trace,
        states[0], states[1], states[2], states[3],
        fc1_w, fc1_b, fc2_w, fc2_b, nlm_T, act, t);
    sync_kernel<<<(BS*NSO)/256, 256, 0, stream>>>(act, idx_ol, idx_or, decay_o,
        aoB, boB, nullptr, syob[t], NSO, t==0);
  }

  // ---- output projection (fused entropy partials) + finalize
  out_gemm3<<<dim3(NBLK), 256, 0, stream>>>(
      syob[0], syob[1], syob[2], syob[3], WoT, out_b, preds, pm, pz, ps);
  ent_final<<<BS*4, 64, 0, stream>>>(pm, pz, ps, certs);
}